// Round 15
// baseline (172.908 us; speedup 1.0000x reference)
//
#include <hip/hip_runtime.h>
#include <hip/hip_bf16.h>
#include <cstddef>

#define N_E 400000
#define N_V 50000
#define NEG_SLOPE 0.01f
#define BN_EPS 1e-5f
#define NT2 (N_E / 128)

typedef __attribute__((ext_vector_type(8))) short bf16x8;
typedef __attribute__((ext_vector_type(4))) short s16x4;
typedef __attribute__((ext_vector_type(4))) float f32x4;

// ws layout (bytes)
#define PART_OFF   0            // 64 replicas * 256 f32 = 65536 B
#define SCALE_OFF  65536        // 256 f32 (scale[128], shift[128])
#define WT_OFF     66560        // bf16 weights, packed in MFMA A-frag chunks
// wt shorts: W1a 8192 @0 | W1b 16384 @8192 | W2 16384 @24576 | W3 16384 @40960
#define META_END   181248
#define Y_BYTES    12800000ULL  // 50000*128*2
#define H_BYTES    102400000ULL // 400000*128*2
#define OUT_BYTES  204800000ULL

// XOR-swizzled LDS addressing (8-short chunks)
#define SWX(row, chunk) ((row) * 64 + ((((chunk) ^ ((row) & 7))) << 3))
#define SWM(row, chunk) ((row) * 128 + ((((chunk) ^ ((row) & 7))) << 3))

__device__ __forceinline__ unsigned short f2bf(float f) {
  unsigned u = __builtin_bit_cast(unsigned, f);
  u += 0x7fffu + ((u >> 16) & 1u);            // RNE
  return (unsigned short)(u >> 16);
}
__device__ __forceinline__ float bf2f(unsigned short s) {
  return __builtin_bit_cast(float, (unsigned)s << 16);
}
__device__ __forceinline__ float lrelu(float x) {
  return x >= 0.f ? x : NEG_SLOPE * x;
}
// pack 2 f32 -> 2 bf16 via HW cvt
__device__ __forceinline__ unsigned pk2(float lo, float hi) {
  unsigned r;
  asm("v_cvt_pk_bf16_f32 %0, %1, %2" : "=v"(r) : "v"(lo), "v"(hi));
  return r;
}
__device__ __forceinline__ int addbf(int a, int b) {
  unsigned ua = (unsigned)a, ub = (unsigned)b;
  float l = __builtin_bit_cast(float, ua << 16) + __builtin_bit_cast(float, ub << 16);
  float h = __builtin_bit_cast(float, ua & 0xffff0000u) +
            __builtin_bit_cast(float, ub & 0xffff0000u);
  return (int)pk2(l, h);
}

// ---- gnn9: 128-edge tile, 1024 thr / 16 waves; wave w = feature-tile (w>>1),
// edge-half (w&1). Same per-wave shape as gnn8 (acc[4], k-outer JIT frags, no
// spill at 64-reg budget); LDS 80KB -> 2 blocks/CU = 2048 thr/CU (max). Blocks
// 6250->3125: halves the per-block serial gather chains + barrier drains.
template<bool USEWS>
__global__ __launch_bounds__(1024, 8) void gnn9(
    const float* __restrict__ edgef, const int* __restrict__ srcI,
    const int* __restrict__ dstI, const short* __restrict__ ybuf,
    const float* __restrict__ b1, const float* __restrict__ b2,
    const float* __restrict__ b3, const short* __restrict__ wt,
    float* __restrict__ partials, short* __restrict__ hout,
    float* __restrict__ fout) {
  __shared__ short sX[128 * 64];   // ef tile (swizzled)      16 KB
  __shared__ short sY[128 * 128];  // ysum -> h2              32 KB
  __shared__ short sZ[128 * 128];  // h1 -> h3                32 KB

  const int tid = threadIdx.x;
  const int lane = tid & 63;
  const int w = tid >> 6;          // wave 0..15
  const int col = lane & 15;
  const int lq = lane >> 4;        // 0..3
  const int t = blockIdx.x;
  const int r8 = tid >> 3, c8 = tid & 7;   // staging: 8 thr per edge row (128 rows)
  const int eb = (w & 1) * 64;             // edge-half base
  const int f0 = (w >> 1) * 16 + lq * 4;   // feature base
  const int ch = f0 >> 3, sub = f0 & 7;

  // ---- stage: ef -> sX, y[src]+y[dst] -> sY ----
  {
    int e = t * 128 + r8;
    int si = srcI[e], di = dstI[e];
    const float4* efp = (const float4*)(edgef + (size_t)e * 64) + c8 * 2;
    float4 e0 = efp[0], e1 = efp[1];
    const int4* yps = (const int4*)(ybuf + (size_t)si * 128) + c8 * 2;
    const int4* ypd = (const int4*)(ybuf + (size_t)di * 128) + c8 * 2;
    int4 a0 = yps[0], a1 = yps[1];
    int4 d0 = ypd[0], d1 = ypd[1];
    int4 x;
    x.x = (int)pk2(e0.x, e0.y); x.y = (int)pk2(e0.z, e0.w);
    x.z = (int)pk2(e1.x, e1.y); x.w = (int)pk2(e1.z, e1.w);
    *(int4*)(sX + SWX(r8, c8)) = x;
    int4 y0, y1;
    y0.x = addbf(a0.x, d0.x); y0.y = addbf(a0.y, d0.y);
    y0.z = addbf(a0.z, d0.z); y0.w = addbf(a0.w, d0.w);
    y1.x = addbf(a1.x, d1.x); y1.y = addbf(a1.y, d1.y);
    y1.z = addbf(a1.z, d1.z); y1.w = addbf(a1.w, d1.w);
    *(int4*)(sY + SWM(r8, c8 * 2)) = y0;
    *(int4*)(sY + SWM(r8, c8 * 2 + 1)) = y1;
  }

  f32x4 acc[4];
  #pragma unroll
  for (int i = 0; i < 4; ++i) acc[i] = (f32x4){0.f, 0.f, 0.f, 0.f};
  float sE[4] = {0.f, 0.f, 0.f, 0.f}, sQv[4] = {0.f, 0.f, 0.f, 0.f};

  __syncthreads();                     // (1) staged

  // ---- L1 (K=64): B from sX; epi(+y from sY) -> sZ ----
  {
    #pragma unroll
    for (int s = 0; s < 2; ++s) {
      bf16x8 f1 = *(const bf16x8*)(wt + ((((w >> 1) * 2 + s) << 9) + lane * 8));
      #pragma unroll
      for (int et = 0; et < 4; ++et) {
        bf16x8 b = *(const bf16x8*)(sX + SWX(eb + et * 16 + col, lq + s * 4));
        acc[et] = __builtin_amdgcn_mfma_f32_16x16x32_bf16(f1, b, acc[et], 0, 0, 0);
      }
    }
    float4 bb = *(const float4*)(b1 + f0);
    #pragma unroll
    for (int et = 0; et < 4; ++et) {
      const int edge = eb + et * 16 + col;
      short4 q = *(const short4*)(sY + SWM(edge, ch) + sub);
      f32x4 a = acc[et];
      float v0 = lrelu(a[0] + bb.x + bf2f((unsigned short)q.x));
      float v1 = lrelu(a[1] + bb.y + bf2f((unsigned short)q.y));
      float v2 = lrelu(a[2] + bb.z + bf2f((unsigned short)q.z));
      float v3 = lrelu(a[3] + bb.w + bf2f((unsigned short)q.w));
      *(int2*)(sZ + SWM(edge, ch) + sub) = make_int2((int)pk2(v0, v1), (int)pk2(v2, v3));
      acc[et] = (f32x4){0.f, 0.f, 0.f, 0.f};
    }
  }
  __syncthreads();                     // (2) h1 in sZ; y consumed

  // ---- L2 (K=128): B from sZ; epi -> sY ----
  {
    #pragma unroll
    for (int s = 0; s < 4; ++s) {
      bf16x8 f2 = *(const bf16x8*)(wt + 24576 + ((((w >> 1) * 4 + s) << 9) + lane * 8));
      #pragma unroll
      for (int et = 0; et < 4; ++et) {
        bf16x8 b = *(const bf16x8*)(sZ + SWM(eb + et * 16 + col, lq + s * 4));
        acc[et] = __builtin_amdgcn_mfma_f32_16x16x32_bf16(f2, b, acc[et], 0, 0, 0);
      }
    }
    float4 bb = *(const float4*)(b2 + f0);
    #pragma unroll
    for (int et = 0; et < 4; ++et) {
      const int edge = eb + et * 16 + col;
      f32x4 a = acc[et];
      float v0 = lrelu(a[0] + bb.x), v1 = lrelu(a[1] + bb.y);
      float v2 = lrelu(a[2] + bb.z), v3 = lrelu(a[3] + bb.w);
      *(int2*)(sY + SWM(edge, ch) + sub) = make_int2((int)pk2(v0, v1), (int)pk2(v2, v3));
      acc[et] = (f32x4){0.f, 0.f, 0.f, 0.f};
    }
  }
  __syncthreads();                     // (3) h2 in sY

  // ---- L3 (K=128): B from sY; epi + stats -> sZ (staged) ----
  {
    #pragma unroll
    for (int s = 0; s < 4; ++s) {
      bf16x8 f3 = *(const bf16x8*)(wt + 40960 + ((((w >> 1) * 4 + s) << 9) + lane * 8));
      #pragma unroll
      for (int et = 0; et < 4; ++et) {
        bf16x8 b = *(const bf16x8*)(sY + SWM(eb + et * 16 + col, lq + s * 4));
        acc[et] = __builtin_amdgcn_mfma_f32_16x16x32_bf16(f3, b, acc[et], 0, 0, 0);
      }
    }
    float4 bb = *(const float4*)(b3 + f0);
    #pragma unroll
    for (int et = 0; et < 4; ++et) {
      const int edge = eb + et * 16 + col;
      f32x4 a = acc[et];
      float v0 = lrelu(a[0] + bb.x), v1 = lrelu(a[1] + bb.y);
      float v2 = lrelu(a[2] + bb.z), v3 = lrelu(a[3] + bb.w);
      sE[0] += v0; sQv[0] += v0 * v0;
      sE[1] += v1; sQv[1] += v1 * v1;
      sE[2] += v2; sQv[2] += v2 * v2;
      sE[3] += v3; sQv[3] += v3 * v3;
      *(int2*)(sZ + SWM(edge, ch) + sub) = make_int2((int)pk2(v0, v1), (int)pk2(v2, v3));
    }
  }
  __syncthreads();                     // (4) h3 staged in sZ

  // ---- writeout h3 (fully coalesced 16B stores) ----
  if (USEWS) {
    int4* dst = (int4*)(hout + (size_t)t * 16384);
    dst[r8 * 16 + c8 * 2] = *(const int4*)(sZ + SWM(r8, c8 * 2));
    dst[r8 * 16 + c8 * 2 + 1] = *(const int4*)(sZ + SWM(r8, c8 * 2 + 1));
  } else {
    float4* dst = (float4*)(fout + (size_t)t * 16384);
    #pragma unroll
    for (int j = 0; j < 2; ++j) {
      int4 tv = *(const int4*)(sZ + SWM(r8, c8 * 2 + j));
      float4 o0, o1;
      o0.x = bf2f((unsigned short)((unsigned)tv.x & 0xffffu));
      o0.y = bf2f((unsigned short)((unsigned)tv.x >> 16));
      o0.z = bf2f((unsigned short)((unsigned)tv.y & 0xffffu));
      o0.w = bf2f((unsigned short)((unsigned)tv.y >> 16));
      o1.x = bf2f((unsigned short)((unsigned)tv.z & 0xffffu));
      o1.y = bf2f((unsigned short)((unsigned)tv.z >> 16));
      o1.z = bf2f((unsigned short)((unsigned)tv.w & 0xffffu));
      o1.w = bf2f((unsigned short)((unsigned)tv.w >> 16));
      dst[r8 * 32 + c8 * 4 + j * 2] = o0;
      dst[r8 * 32 + c8 * 4 + j * 2 + 1] = o1;
    }
  }

  // ---- stats: butterfly over edge lanes (low 4 bits), then atomics ----
  #pragma unroll
  for (int m = 1; m <= 8; m <<= 1) {
    #pragma unroll
    for (int i = 0; i < 4; ++i) {
      sE[i] += __shfl_xor(sE[i], m, 64);
      sQv[i] += __shfl_xor(sQv[i], m, 64);
    }
  }
  if (col == 0) {
    float* pp = partials + (t & 63) * 256;
    #pragma unroll
    for (int i = 0; i < 4; ++i) {
      atomicAdd(&pp[f0 + i], sE[i]);
      atomicAdd(&pp[128 + f0 + i], sQv[i]);
    }
  }
}

// ---- per-node precompute: y = nf * W1b  (bf16 out) ----
__global__ __launch_bounds__(256) void nodeK(const float* __restrict__ nodef,
                                             const short* __restrict__ wt,
                                             short* __restrict__ y) {
  __shared__ short sN[64 * 136];
  const int tid = threadIdx.x;
  const int lane = tid & 63;
  const int w = tid >> 6;
  const int n0 = blockIdx.x * 64;
  const int r = tid >> 2, p4 = tid & 3;
  {
    int v = n0 + r;
    int vc = v < N_V ? v : N_V - 1;
    const float4* np = (const float4*)(nodef + (size_t)vc * 128) + p4 * 8;
    #pragma unroll
    for (int j = 0; j < 8; ++j) {
      float4 a = np[j];
      *(int2*)(sN + r * 136 + p4 * 32 + j * 4) =
          make_int2((int)pk2(a.x, a.y), (int)pk2(a.z, a.w));
    }
  }
  __syncthreads();
  const short* wb = wt + 8192;
  f32x4 acc[8];
  #pragma unroll
  for (int i = 0; i < 8; ++i) acc[i] = (f32x4){0.f, 0.f, 0.f, 0.f};
  const int col = lane & 15;
  const int kb = (lane >> 4) * 8;
  #pragma unroll
  for (int nt = 0; nt < 2; ++nt)
    #pragma unroll
    for (int s = 0; s < 4; ++s) {
      bf16x8 fr = *(const bf16x8*)(wb + ((((w * 2 + nt) * 4 + s) << 9) + lane * 8));
      #pragma unroll
      for (int et = 0; et < 4; ++et) {
        bf16x8 b = *(const bf16x8*)(sN + (et * 16 + col) * 136 + kb + s * 32);
        acc[nt * 4 + et] = __builtin_amdgcn_mfma_f32_16x16x32_bf16(fr, b, acc[nt * 4 + et], 0, 0, 0);
      }
    }
  __syncthreads();   // sN input reads done
  {
    const int fb = (lane >> 4) * 4;
    #pragma unroll
    for (int nt = 0; nt < 2; ++nt) {
      const int f0 = w * 32 + nt * 16 + fb;
      #pragma unroll
      for (int et = 0; et < 4; ++et) {
        f32x4 a = acc[nt * 4 + et];
        *(int2*)(sN + (et * 16 + col) * 136 + f0) =
            make_int2((int)pk2(a[0], a[1]), (int)pk2(a[2], a[3]));
      }
    }
  }
  __syncthreads();
  if (n0 + r < N_V) {
    #pragma unroll
    for (int j = 0; j < 4; ++j) {
      int4 tv = *(const int4*)(sN + r * 136 + p4 * 32 + j * 8);
      *(int4*)(y + (size_t)(n0 + r) * 128 + p4 * 32 + j * 8) = tv;
    }
  }
}

// ---- weight pack + partials zero ----
__global__ __launch_bounds__(256) void prepK(const float* __restrict__ W1,
                                             const float* __restrict__ W2,
                                             const float* __restrict__ W3,
                                             short* __restrict__ wt,
                                             float* __restrict__ partials) {
  int b = blockIdx.x, t = threadIdx.x;
  if (b < 64) { partials[b * 256 + t] = 0.f; return; }
  int g = (b - 64) * 256 + t;
  for (int fi = g; fi < 57344; fi += 32 * 256) {
    float val;
    if (fi < 8192) {                       // W1a: 8 tiles x 2 ksteps (K=64)
      int c = fi >> 9, r = fi & 511;
      int l = r >> 3, j = r & 7;
      int tt = c >> 1, s = c & 1;
      int n = tt * 16 + (l & 15);
      int k = s * 32 + (l >> 4) * 8 + j;
      val = W1[k * 128 + n];
    } else if (fi < 24576) {               // W1b: 8 tiles x 4 ksteps (rows 64..191)
      int f2 = fi - 8192;
      int c = f2 >> 9, r = f2 & 511;
      int l = r >> 3, j = r & 7;
      int tt = c >> 2, s = c & 3;
      int n = tt * 16 + (l & 15);
      int k = s * 32 + (l >> 4) * 8 + j;
      val = W1[(64 + k) * 128 + n];
    } else if (fi < 40960) {               // W2
      int f2 = fi - 24576;
      int c = f2 >> 9, r = f2 & 511;
      int l = r >> 3, j = r & 7;
      int tt = c >> 2, s = c & 3;
      int n = tt * 16 + (l & 15);
      int k = s * 32 + (l >> 4) * 8 + j;
      val = W2[k * 128 + n];
    } else {                               // W3
      int f3 = fi - 40960;
      int c = f3 >> 9, r = f3 & 511;
      int l = r >> 3, j = r & 7;
      int tt = c >> 2, s = c & 3;
      int n = tt * 16 + (l & 15);
      int k = s * 32 + (l >> 4) * 8 + j;
      val = W3[k * 128 + n];
    }
    wt[fi] = (short)f2bf(val);
  }
}

// ---- fused stats + BN apply; reverse traversal exploits L3-resident h tail.
template<bool USEWS>
__global__ __launch_bounds__(256) void applyK(const short* __restrict__ h,
                                              const float* __restrict__ partials,
                                              const float* __restrict__ gamma,
                                              const float* __restrict__ beta,
                                              float* out) {
  __shared__ float sS[256];
  const int t = threadIdx.x;
  {
    float a = 0.f;
    #pragma unroll 8
    for (int r = 0; r < 64; ++r) a += partials[r * 256 + t];
    sS[t] = a;
  }
  __syncthreads();
  if (t < 128) {
    float S = sS[t], S2 = sS[t + 128];
    float mean = S / (float)N_E;
    float var = S2 / (float)N_E - mean * mean;   // biased, matches reference
    float inv = rsqrtf(var + BN_EPS);
    float sc = gamma[t] * inv;
    sS[t] = sc;                                  // own-slot rewrite: no hazard
    sS[t + 128] = beta[t] - mean * sc;
  }
  __syncthreads();

  const int TOT4 = N_E * 128 / 4;                // 12,800,000 (mult of 32)
  int j0 = blockIdx.x * 256 + t;
  int c4 = (TOT4 - 1 - j0) & 31;                 // const per thread
  float4 sc = *(const float4*)(sS + c4 * 4);
  float4 sh = *(const float4*)(sS + 128 + c4 * 4);
  int stride = gridDim.x * 256;
  for (int j = j0; j < TOT4; j += stride) {
    int jj = TOT4 - 1 - j;                       // reverse traversal
    f32x4 v;
    if (USEWS) {
      s16x4 s = *(const s16x4*)(h + (size_t)jj * 4);
      v[0] = bf2f((unsigned short)s[0]) * sc.x + sh.x;
      v[1] = bf2f((unsigned short)s[1]) * sc.y + sh.y;
      v[2] = bf2f((unsigned short)s[2]) * sc.z + sh.z;
      v[3] = bf2f((unsigned short)s[3]) * sc.w + sh.w;
    } else {
      f32x4 hv = *((const f32x4*)out + jj);
      v[0] = hv[0] * sc.x + sh.x;
      v[1] = hv[1] * sc.y + sh.y;
      v[2] = hv[2] * sc.z + sh.z;
      v[3] = hv[3] * sc.w + sh.w;
    }
    __builtin_nontemporal_store(v, (f32x4*)out + jj);
  }
}

extern "C" void kernel_launch(void* const* d_in, const int* in_sizes, int n_in,
                              void* d_out, int out_size, void* d_ws, size_t ws_size,
                              hipStream_t stream) {
  const float* nodef = (const float*)d_in[0];
  const float* edgef = (const float*)d_in[1];
  const int* srcI = (const int*)d_in[2];
  const int* dstI = (const int*)d_in[3];
  const float* W1 = (const float*)d_in[4];
  const float* b1 = (const float*)d_in[5];
  const float* W2 = (const float*)d_in[6];
  const float* b2 = (const float*)d_in[7];
  const float* W3 = (const float*)d_in[8];
  const float* b3 = (const float*)d_in[9];
  const float* gamma = (const float*)d_in[10];
  const float* beta = (const float*)d_in[11];
  float* out = (float*)d_out;
  char* ws = (char*)d_ws;

  float* partials = (float*)(ws + PART_OFF);
  short* wt = (short*)(ws + WT_OFF);
  short* ybuf;
  short* h = nullptr;
  bool usews;
  if (ws_size >= (size_t)META_END + Y_BYTES + H_BYTES) {
    ybuf = (short*)(ws + META_END);
    h = (short*)(ws + META_END + Y_BYTES);
    usews = true;
  } else if (ws_size >= (size_t)META_END + H_BYTES) {
    h = (short*)(ws + META_END);
    ybuf = (short*)((char*)d_out + OUT_BYTES - Y_BYTES);  // tail of out; rewritten by applyK last
    usews = true;
  } else {
    ybuf = (short*)(ws + META_END);
    usews = false;
  }

  prepK<<<96, 256, 0, stream>>>(W1, W2, W3, wt, partials);
  nodeK<<<782, 256, 0, stream>>>(nodef, wt, ybuf);
  if (usews) {
    gnn9<true><<<NT2, 1024, 0, stream>>>(edgef, srcI, dstI, ybuf, b1, b2, b3,
                                         wt, partials, h, out);
    applyK<true><<<1024, 256, 0, stream>>>(h, partials, gamma, beta, out);
  } else {
    gnn9<false><<<NT2, 1024, 0, stream>>>(edgef, srcI, dstI, ybuf, b1, b2, b3,
                                          wt, partials, h, out);
    applyK<false><<<1024, 256, 0, stream>>>(h, partials, gamma, beta, out);
  }
}

// Round 16
// 153.733 us; speedup vs baseline: 1.1247x; 1.1247x over previous
//
#include <hip/hip_runtime.h>
#include <hip/hip_bf16.h>
#include <cstddef>

#define N_E 400000
#define N_V 50000
#define NEG_SLOPE 0.01f
#define BN_EPS 1e-5f
#define NT (N_E / 64)

typedef __attribute__((ext_vector_type(8))) short bf16x8;
typedef __attribute__((ext_vector_type(4))) short s16x4;
typedef __attribute__((ext_vector_type(4))) float f32x4;

// ws layout (bytes)
#define PART_OFF   0            // 64 replicas * 256 f32 = 65536 B
#define SCALE_OFF  65536        // 256 f32 (scale[128], shift[128])
#define WT_OFF     66560        // bf16 weights, packed in MFMA A-frag chunks
// wt shorts: W1a 8192 @0 | W1b 16384 @8192 | W2 16384 @24576 | W3 16384 @40960
#define META_END   181248
#define Y_BYTES    12800000ULL  // 50000*128*2
#define H_BYTES    102400000ULL // 400000*128*2
#define OUT_BYTES  204800000ULL

// XOR-swizzled LDS addressing (8-short chunks)
#define SWX(row, chunk) ((row) * 64 + ((((chunk) ^ ((row) & 7))) << 3))
#define SWM(row, chunk) ((row) * 128 + ((((chunk) ^ ((row) & 7))) << 3))

__device__ __forceinline__ unsigned short f2bf(float f) {
  unsigned u = __builtin_bit_cast(unsigned, f);
  u += 0x7fffu + ((u >> 16) & 1u);            // RNE
  return (unsigned short)(u >> 16);
}
__device__ __forceinline__ float bf2f(unsigned short s) {
  return __builtin_bit_cast(float, (unsigned)s << 16);
}
__device__ __forceinline__ float lrelu(float x) {
  return x >= 0.f ? x : NEG_SLOPE * x;
}
// pack 2 f32 -> 2 bf16 via HW cvt
__device__ __forceinline__ unsigned pk2(float lo, float hi) {
  unsigned r;
  asm("v_cvt_pk_bf16_f32 %0, %1, %2" : "=v"(r) : "v"(lo), "v"(hi));
  return r;
}
__device__ __forceinline__ int addbf(int a, int b) {
  unsigned ua = (unsigned)a, ub = (unsigned)b;
  float l = __builtin_bit_cast(float, ua << 16) + __builtin_bit_cast(float, ub << 16);
  float h = __builtin_bit_cast(float, ua & 0xffff0000u) +
            __builtin_bit_cast(float, ub & 0xffff0000u);
  return (int)pk2(l, h);
}

// ---- gnn8: 512 thr / 8 waves, 1 feature-tile per wave, 1 tile per block.
// JIT k-outer fragment loops (no remat/spill) + LDS-staged coalesced h3 write.
// (Round-15 lesson: 1024-thr/16-wave variant re-triggered the 32-VGPR squeeze
// and regressed 25% — this 512-thr shape is the empirical optimum.)
template<bool USEWS>
__global__ __launch_bounds__(512, 8) void gnn8(
    const float* __restrict__ edgef, const int* __restrict__ srcI,
    const int* __restrict__ dstI, const short* __restrict__ ybuf,
    const float* __restrict__ b1, const float* __restrict__ b2,
    const float* __restrict__ b3, const short* __restrict__ wt,
    float* __restrict__ partials, short* __restrict__ hout,
    float* __restrict__ fout) {
  __shared__ short sX[64 * 64];    // ef tile (swizzled)
  __shared__ short sY[64 * 128];   // ysum -> h2
  __shared__ short sZ[64 * 128];   // h1 -> h3

  const int tid = threadIdx.x;
  const int lane = tid & 63;
  const int w = tid >> 6;          // wave = feature tile 0..7
  const int col = lane & 15;       // edge-in-subtile
  const int lq = lane >> 4;        // 0..3
  const int t = blockIdx.x;
  const int r8 = tid >> 3, c8 = tid & 7;   // staging: 8 thr per edge row
  const int f0 = w * 16 + lq * 4;
  const int ch = f0 >> 3, sub = f0 & 7;

  // ---- stage: ef -> sX, y[src]+y[dst] -> sY ----
  {
    int e = t * 64 + r8;
    int si = srcI[e], di = dstI[e];
    const float4* efp = (const float4*)(edgef + (size_t)e * 64) + c8 * 2;
    float4 e0 = efp[0], e1 = efp[1];
    const int4* yps = (const int4*)(ybuf + (size_t)si * 128) + c8 * 2;
    const int4* ypd = (const int4*)(ybuf + (size_t)di * 128) + c8 * 2;
    int4 a0 = yps[0], a1 = yps[1];
    int4 d0 = ypd[0], d1 = ypd[1];
    int4 x;
    x.x = (int)pk2(e0.x, e0.y); x.y = (int)pk2(e0.z, e0.w);
    x.z = (int)pk2(e1.x, e1.y); x.w = (int)pk2(e1.z, e1.w);
    *(int4*)(sX + SWX(r8, c8)) = x;
    int4 y0, y1;
    y0.x = addbf(a0.x, d0.x); y0.y = addbf(a0.y, d0.y);
    y0.z = addbf(a0.z, d0.z); y0.w = addbf(a0.w, d0.w);
    y1.x = addbf(a1.x, d1.x); y1.y = addbf(a1.y, d1.y);
    y1.z = addbf(a1.z, d1.z); y1.w = addbf(a1.w, d1.w);
    *(int4*)(sY + SWM(r8, c8 * 2)) = y0;
    *(int4*)(sY + SWM(r8, c8 * 2 + 1)) = y1;
  }

  f32x4 acc[4];
  #pragma unroll
  for (int i = 0; i < 4; ++i) acc[i] = (f32x4){0.f, 0.f, 0.f, 0.f};
  float sE[4] = {0.f, 0.f, 0.f, 0.f}, sQv[4] = {0.f, 0.f, 0.f, 0.f};

  __syncthreads();                     // (1) staged

  // ---- L1 (K=64): B from sX; epi(+y from sY) -> sZ ----
  {
    #pragma unroll
    for (int s = 0; s < 2; ++s) {
      bf16x8 f1 = *(const bf16x8*)(wt + (((w * 2 + s) << 9) + lane * 8));
      #pragma unroll
      for (int et = 0; et < 4; ++et) {
        bf16x8 b = *(const bf16x8*)(sX + SWX(et * 16 + col, lq + s * 4));
        acc[et] = __builtin_amdgcn_mfma_f32_16x16x32_bf16(f1, b, acc[et], 0, 0, 0);
      }
    }
    float4 bb = *(const float4*)(b1 + f0);
    #pragma unroll
    for (int et = 0; et < 4; ++et) {
      const int edge = et * 16 + col;
      short4 q = *(const short4*)(sY + SWM(edge, ch) + sub);
      f32x4 a = acc[et];
      float v0 = lrelu(a[0] + bb.x + bf2f((unsigned short)q.x));
      float v1 = lrelu(a[1] + bb.y + bf2f((unsigned short)q.y));
      float v2 = lrelu(a[2] + bb.z + bf2f((unsigned short)q.z));
      float v3 = lrelu(a[3] + bb.w + bf2f((unsigned short)q.w));
      *(int2*)(sZ + SWM(edge, ch) + sub) = make_int2((int)pk2(v0, v1), (int)pk2(v2, v3));
      acc[et] = (f32x4){0.f, 0.f, 0.f, 0.f};
    }
  }
  __syncthreads();                     // (2) h1 in sZ; y consumed

  // ---- L2 (K=128): B from sZ; epi -> sY ----
  {
    #pragma unroll
    for (int s = 0; s < 4; ++s) {
      bf16x8 f2 = *(const bf16x8*)(wt + 24576 + (((w * 4 + s) << 9) + lane * 8));
      #pragma unroll
      for (int et = 0; et < 4; ++et) {
        bf16x8 b = *(const bf16x8*)(sZ + SWM(et * 16 + col, lq + s * 4));
        acc[et] = __builtin_amdgcn_mfma_f32_16x16x32_bf16(f2, b, acc[et], 0, 0, 0);
      }
    }
    float4 bb = *(const float4*)(b2 + f0);
    #pragma unroll
    for (int et = 0; et < 4; ++et) {
      const int edge = et * 16 + col;
      f32x4 a = acc[et];
      float v0 = lrelu(a[0] + bb.x), v1 = lrelu(a[1] + bb.y);
      float v2 = lrelu(a[2] + bb.z), v3 = lrelu(a[3] + bb.w);
      *(int2*)(sY + SWM(edge, ch) + sub) = make_int2((int)pk2(v0, v1), (int)pk2(v2, v3));
      acc[et] = (f32x4){0.f, 0.f, 0.f, 0.f};
    }
  }
  __syncthreads();                     // (3) h2 in sY

  // ---- L3 (K=128): B from sY; epi + stats -> sZ (staged) ----
  {
    #pragma unroll
    for (int s = 0; s < 4; ++s) {
      bf16x8 f3 = *(const bf16x8*)(wt + 40960 + (((w * 4 + s) << 9) + lane * 8));
      #pragma unroll
      for (int et = 0; et < 4; ++et) {
        bf16x8 b = *(const bf16x8*)(sY + SWM(et * 16 + col, lq + s * 4));
        acc[et] = __builtin_amdgcn_mfma_f32_16x16x32_bf16(f3, b, acc[et], 0, 0, 0);
      }
    }
    float4 bb = *(const float4*)(b3 + f0);
    #pragma unroll
    for (int et = 0; et < 4; ++et) {
      const int edge = et * 16 + col;
      f32x4 a = acc[et];
      float v0 = lrelu(a[0] + bb.x), v1 = lrelu(a[1] + bb.y);
      float v2 = lrelu(a[2] + bb.z), v3 = lrelu(a[3] + bb.w);
      sE[0] += v0; sQv[0] += v0 * v0;
      sE[1] += v1; sQv[1] += v1 * v1;
      sE[2] += v2; sQv[2] += v2 * v2;
      sE[3] += v3; sQv[3] += v3 * v3;
      *(int2*)(sZ + SWM(edge, ch) + sub) = make_int2((int)pk2(v0, v1), (int)pk2(v2, v3));
    }
  }
  __syncthreads();                     // (4) h3 staged in sZ

  // ---- writeout h3 (fully coalesced 16B stores) ----
  if (USEWS) {
    int4* dst = (int4*)(hout + (size_t)t * 8192);
    dst[r8 * 16 + c8 * 2] = *(const int4*)(sZ + SWM(r8, c8 * 2));
    dst[r8 * 16 + c8 * 2 + 1] = *(const int4*)(sZ + SWM(r8, c8 * 2 + 1));
  } else {
    float4* dst = (float4*)(fout + (size_t)t * 8192);
    #pragma unroll
    for (int j = 0; j < 2; ++j) {
      int4 tv = *(const int4*)(sZ + SWM(r8, c8 * 2 + j));
      float4 o0, o1;
      o0.x = bf2f((unsigned short)((unsigned)tv.x & 0xffffu));
      o0.y = bf2f((unsigned short)((unsigned)tv.x >> 16));
      o0.z = bf2f((unsigned short)((unsigned)tv.y & 0xffffu));
      o0.w = bf2f((unsigned short)((unsigned)tv.y >> 16));
      o1.x = bf2f((unsigned short)((unsigned)tv.z & 0xffffu));
      o1.y = bf2f((unsigned short)((unsigned)tv.z >> 16));
      o1.z = bf2f((unsigned short)((unsigned)tv.w & 0xffffu));
      o1.w = bf2f((unsigned short)((unsigned)tv.w >> 16));
      dst[r8 * 32 + c8 * 4 + j * 2] = o0;
      dst[r8 * 32 + c8 * 4 + j * 2 + 1] = o1;
    }
  }

  // ---- stats: butterfly over edge lanes (low 4 bits), then atomics ----
  #pragma unroll
  for (int m = 1; m <= 8; m <<= 1) {
    #pragma unroll
    for (int i = 0; i < 4; ++i) {
      sE[i] += __shfl_xor(sE[i], m, 64);
      sQv[i] += __shfl_xor(sQv[i], m, 64);
    }
  }
  if (col == 0) {
    float* pp = partials + (t & 63) * 256;
    #pragma unroll
    for (int i = 0; i < 4; ++i) {
      atomicAdd(&pp[f0 + i], sE[i]);
      atomicAdd(&pp[128 + f0 + i], sQv[i]);
    }
  }
}

// ---- per-node precompute: y = nf * W1b  (bf16 out) ----
__global__ __launch_bounds__(256) void nodeK(const float* __restrict__ nodef,
                                             const short* __restrict__ wt,
                                             short* __restrict__ y) {
  __shared__ short sN[64 * 136];
  const int tid = threadIdx.x;
  const int lane = tid & 63;
  const int w = tid >> 6;
  const int n0 = blockIdx.x * 64;
  const int r = tid >> 2, p4 = tid & 3;
  {
    int v = n0 + r;
    int vc = v < N_V ? v : N_V - 1;
    const float4* np = (const float4*)(nodef + (size_t)vc * 128) + p4 * 8;
    #pragma unroll
    for (int j = 0; j < 8; ++j) {
      float4 a = np[j];
      *(int2*)(sN + r * 136 + p4 * 32 + j * 4) =
          make_int2((int)pk2(a.x, a.y), (int)pk2(a.z, a.w));
    }
  }
  __syncthreads();
  const short* wb = wt + 8192;
  f32x4 acc[8];
  #pragma unroll
  for (int i = 0; i < 8; ++i) acc[i] = (f32x4){0.f, 0.f, 0.f, 0.f};
  const int col = lane & 15;
  const int kb = (lane >> 4) * 8;
  #pragma unroll
  for (int nt = 0; nt < 2; ++nt)
    #pragma unroll
    for (int s = 0; s < 4; ++s) {
      bf16x8 fr = *(const bf16x8*)(wb + ((((w * 2 + nt) * 4 + s) << 9) + lane * 8));
      #pragma unroll
      for (int et = 0; et < 4; ++et) {
        bf16x8 b = *(const bf16x8*)(sN + (et * 16 + col) * 136 + kb + s * 32);
        acc[nt * 4 + et] = __builtin_amdgcn_mfma_f32_16x16x32_bf16(fr, b, acc[nt * 4 + et], 0, 0, 0);
      }
    }
  __syncthreads();   // sN input reads done
  {
    const int fb = (lane >> 4) * 4;
    #pragma unroll
    for (int nt = 0; nt < 2; ++nt) {
      const int f0 = w * 32 + nt * 16 + fb;
      #pragma unroll
      for (int et = 0; et < 4; ++et) {
        f32x4 a = acc[nt * 4 + et];
        *(int2*)(sN + (et * 16 + col) * 136 + f0) =
            make_int2((int)pk2(a[0], a[1]), (int)pk2(a[2], a[3]));
      }
    }
  }
  __syncthreads();
  if (n0 + r < N_V) {
    #pragma unroll
    for (int j = 0; j < 4; ++j) {
      int4 tv = *(const int4*)(sN + r * 136 + p4 * 32 + j * 8);
      *(int4*)(y + (size_t)(n0 + r) * 128 + p4 * 32 + j * 8) = tv;
    }
  }
}

// ---- weight pack + partials zero ----
__global__ __launch_bounds__(256) void prepK(const float* __restrict__ W1,
                                             const float* __restrict__ W2,
                                             const float* __restrict__ W3,
                                             short* __restrict__ wt,
                                             float* __restrict__ partials) {
  int b = blockIdx.x, t = threadIdx.x;
  if (b < 64) { partials[b * 256 + t] = 0.f; return; }
  int g = (b - 64) * 256 + t;
  for (int fi = g; fi < 57344; fi += 32 * 256) {
    float val;
    if (fi < 8192) {                       // W1a: 8 tiles x 2 ksteps (K=64)
      int c = fi >> 9, r = fi & 511;
      int l = r >> 3, j = r & 7;
      int tt = c >> 1, s = c & 1;
      int n = tt * 16 + (l & 15);
      int k = s * 32 + (l >> 4) * 8 + j;
      val = W1[k * 128 + n];
    } else if (fi < 24576) {               // W1b: 8 tiles x 4 ksteps (rows 64..191)
      int f2 = fi - 8192;
      int c = f2 >> 9, r = f2 & 511;
      int l = r >> 3, j = r & 7;
      int tt = c >> 2, s = c & 3;
      int n = tt * 16 + (l & 15);
      int k = s * 32 + (l >> 4) * 8 + j;
      val = W1[(64 + k) * 128 + n];
    } else if (fi < 40960) {               // W2
      int f2 = fi - 24576;
      int c = f2 >> 9, r = f2 & 511;
      int l = r >> 3, j = r & 7;
      int tt = c >> 2, s = c & 3;
      int n = tt * 16 + (l & 15);
      int k = s * 32 + (l >> 4) * 8 + j;
      val = W2[k * 128 + n];
    } else {                               // W3
      int f3 = fi - 40960;
      int c = f3 >> 9, r = f3 & 511;
      int l = r >> 3, j = r & 7;
      int tt = c >> 2, s = c & 3;
      int n = tt * 16 + (l & 15);
      int k = s * 32 + (l >> 4) * 8 + j;
      val = W3[k * 128 + n];
    }
    wt[fi] = (short)f2bf(val);
  }
}

// ---- fused stats + BN apply; reverse traversal exploits L3-resident h tail.
template<bool USEWS>
__global__ __launch_bounds__(256) void applyK(const short* __restrict__ h,
                                              const float* __restrict__ partials,
                                              const float* __restrict__ gamma,
                                              const float* __restrict__ beta,
                                              float* out) {
  __shared__ float sS[256];
  const int t = threadIdx.x;
  {
    float a = 0.f;
    #pragma unroll 8
    for (int r = 0; r < 64; ++r) a += partials[r * 256 + t];
    sS[t] = a;
  }
  __syncthreads();
  if (t < 128) {
    float S = sS[t], S2 = sS[t + 128];
    float mean = S / (float)N_E;
    float var = S2 / (float)N_E - mean * mean;   // biased, matches reference
    float inv = rsqrtf(var + BN_EPS);
    float sc = gamma[t] * inv;
    sS[t] = sc;                                  // own-slot rewrite: no hazard
    sS[t + 128] = beta[t] - mean * sc;
  }
  __syncthreads();

  const int TOT4 = N_E * 128 / 4;                // 12,800,000 (mult of 32)
  int j0 = blockIdx.x * 256 + t;
  int c4 = (TOT4 - 1 - j0) & 31;                 // const per thread
  float4 sc = *(const float4*)(sS + c4 * 4);
  float4 sh = *(const float4*)(sS + 128 + c4 * 4);
  int stride = gridDim.x * 256;
  for (int j = j0; j < TOT4; j += stride) {
    int jj = TOT4 - 1 - j;                       // reverse traversal
    f32x4 v;
    if (USEWS) {
      s16x4 s = *(const s16x4*)(h + (size_t)jj * 4);
      v[0] = bf2f((unsigned short)s[0]) * sc.x + sh.x;
      v[1] = bf2f((unsigned short)s[1]) * sc.y + sh.y;
      v[2] = bf2f((unsigned short)s[2]) * sc.z + sh.z;
      v[3] = bf2f((unsigned short)s[3]) * sc.w + sh.w;
    } else {
      f32x4 hv = *((const f32x4*)out + jj);
      v[0] = hv[0] * sc.x + sh.x;
      v[1] = hv[1] * sc.y + sh.y;
      v[2] = hv[2] * sc.z + sh.z;
      v[3] = hv[3] * sc.w + sh.w;
    }
    __builtin_nontemporal_store(v, (f32x4*)out + jj);
  }
}

extern "C" void kernel_launch(void* const* d_in, const int* in_sizes, int n_in,
                              void* d_out, int out_size, void* d_ws, size_t ws_size,
                              hipStream_t stream) {
  const float* nodef = (const float*)d_in[0];
  const float* edgef = (const float*)d_in[1];
  const int* srcI = (const int*)d_in[2];
  const int* dstI = (const int*)d_in[3];
  const float* W1 = (const float*)d_in[4];
  const float* b1 = (const float*)d_in[5];
  const float* W2 = (const float*)d_in[6];
  const float* b2 = (const float*)d_in[7];
  const float* W3 = (const float*)d_in[8];
  const float* b3 = (const float*)d_in[9];
  const float* gamma = (const float*)d_in[10];
  const float* beta = (const float*)d_in[11];
  float* out = (float*)d_out;
  char* ws = (char*)d_ws;

  float* partials = (float*)(ws + PART_OFF);
  short* wt = (short*)(ws + WT_OFF);
  short* ybuf;
  short* h = nullptr;
  bool usews;
  if (ws_size >= (size_t)META_END + Y_BYTES + H_BYTES) {
    ybuf = (short*)(ws + META_END);
    h = (short*)(ws + META_END + Y_BYTES);
    usews = true;
  } else if (ws_size >= (size_t)META_END + H_BYTES) {
    h = (short*)(ws + META_END);
    ybuf = (short*)((char*)d_out + OUT_BYTES - Y_BYTES);  // tail of out; rewritten by applyK last
    usews = true;
  } else {
    ybuf = (short*)(ws + META_END);
    usews = false;
  }

  prepK<<<96, 256, 0, stream>>>(W1, W2, W3, wt, partials);
  nodeK<<<782, 256, 0, stream>>>(nodef, wt, ybuf);
  if (usews) {
    gnn8<true><<<NT, 512, 0, stream>>>(edgef, srcI, dstI, ybuf, b1, b2, b3,
                                       wt, partials, h, out);
    applyK<true><<<1024, 256, 0, stream>>>(h, partials, gamma, beta, out);
  } else {
    gnn8<false><<<NT, 512, 0, stream>>>(edgef, srcI, dstI, ybuf, b1, b2, b3,
                                        wt, partials, h, out);
    applyK<false><<<1024, 256, 0, stream>>>(h, partials, gamma, beta, out);
  }
}